// Round 10
// baseline (142.284 us; speedup 1.0000x reference)
//
#include <hip/hip_runtime.h>

// Guided blur (multichannel guided filter), B=8, C=Cp=3, H=W=512, k=5, eps=1e-4.
// SINGLE fused kernel, LDS-free, barrier-free, FULL-WAVE DPP horizontal taps:
//   - 64-lane wave owns 64 consecutive raw cols; two cascaded 5-tap blurs eat a 4-lane
//     halo per wave side -> 60 valid a-cols, 56 output cols per wave (87.5% lane eff;
//     the 16-lane-segment scheme of r4-r9 got only 8/16 = 50%)
//   - horizontal 5-taps via DPP wave_shl1 (ctrl 0x130) chains: lane u <- u+1, zero-fill
//     at the top (bound_ctrl). Direction convention empirically verified for row_shl in
//     r4-r9 (correctness-passed): *_shl:N => lane u receives lane u+N.
//   - stage 1: vertical 5-row roll of 21 stat channels -> hsum5 -> symmetric 3x3 solve -> a,b
//   - stage 2: hsum5 of a,b; vertical 5-row roll of those 12 -> combine with guidance -> out
//   - trips of 5 rows, template<int I>: all ring indices compile-time => SROA keeps rings
//     in VGPRs.
//   Compile-shape lessons (this session):
//     r5: runtime ring idx -> PromoteAlloca-to-LDS -> 40us LDS-pipe serialization
//     r7: f2 ext-vector arrays in state struct -> failed SROA -> scratch spill (159us)
//     r8: __launch_bounds__(128,4) -> forced 64-VGPR cap -> 440MB spill traffic (213us)
//     r9: occupancy 2->4 waves/SIMD changed nothing (VALUBusy stuck ~57%): the kernel is
//         VALU-inst-count bound -> this round cuts inst/output ~42% via lane efficiency.
//   Proven safe form: scalar floats, constexpr indices, block=64, __launch_bounds__(64,2).
// No d_ws usage.

namespace {

constexpr int BN = 8;
constexpr int HH = 512;
constexpr int WW = 512;
constexpr int CSZ = HH * WW;
constexpr float GEPS = 1e-4f;
constexpr int OUTW = 56;            // output cols per wave (64 - 2*4 halo)
constexpr int SR   = 16;            // output rows per wave strip (reads SR+8 raw rows)

__device__ __forceinline__ int refl(int i, int n) {
    // jnp.pad reflect: -1 -> 1, -2 -> 2, n -> n-2, n+1 -> n-3
    if (i < 0) i = -i;
    if (i >= n) i = 2 * n - 2 - i;
    return i;
}

// DPP wave_shl1: lane u receives lane u+1; lane 63 gets 0 (bound_ctrl).
__device__ __forceinline__ float wshl1(float v) {
    return __builtin_bit_cast(float,
        __builtin_amdgcn_update_dpp(0, __builtin_bit_cast(int, v),
                                    0x130, 0xF, 0xF, true));
}
// lane u gets v[u]+v[u+1]+v[u+2]+v[u+3]+v[u+4]; valid for u <= 59.
__device__ __forceinline__ float hsum5(float v) {
    float a1 = wshl1(v);
    float a2 = wshl1(a1);
    float a3 = wshl1(a2);
    float a4 = wshl1(a3);
    return ((v + a1) + (a2 + a3)) + a4;
}

struct St {
    float V1[21];      // stage-1 vertical window sums (21 stat channels)
    float r1[5][6];    // last 5 raw rows (6 channels)
    float V2[12];      // stage-2 vertical sums of hsum'd a,b
    float r2[5][12];   // last 5 hsum'd a,b rows
};

struct Ctx {
    const float *g0, *g1, *g2, *p0, *p1, *p2;  // channel base pointers
    float *o0, *o1, *o2;
    int yb, xr, xs;
    bool wr;
};

// One raw row. rr = 5*t + I. Ring slots use constexpr I ((5t+I)%5 == I).
template <int I, bool SUB1, bool SOLVE, bool V2SUB, bool OUT>
__device__ __forceinline__ void row(St& st, const Ctx& cx, int t) {
    const int rr = 5 * t + I;
    const int y = refl(cx.yb - 4 + rr, HH);
    const int off = y * WW + cx.xr;
    float c0 = cx.g0[off], c1 = cx.g1[off], c2 = cx.g2[off];
    float c3 = cx.p0[off], c4 = cx.p1[off], c5 = cx.p2[off];

    // guidance for this iter's output row — issued early to cover latency
    float go0 = 0.f, go1 = 0.f, go2 = 0.f;
    int oOff = 0;
    if constexpr (OUT) {
        oOff = (cx.yb + rr - 8) * WW + cx.xs;
        go0 = cx.g0[oOff]; go1 = cx.g1[oOff]; go2 = cx.g2[oOff];
    }

    // add current raw row
    st.V1[0] += c0; st.V1[1] += c1; st.V1[2] += c2;
    st.V1[3] += c3; st.V1[4] += c4; st.V1[5] += c5;
    st.V1[6]  += c0 * c0; st.V1[7]  += c0 * c1; st.V1[8]  += c0 * c2;
    st.V1[9]  += c1 * c1; st.V1[10] += c1 * c2; st.V1[11] += c2 * c2;
    st.V1[12] += c0 * c3; st.V1[13] += c0 * c4; st.V1[14] += c0 * c5;
    st.V1[15] += c1 * c3; st.V1[16] += c1 * c4; st.V1[17] += c1 * c5;
    st.V1[18] += c2 * c3; st.V1[19] += c2 * c4; st.V1[20] += c2 * c5;

    if constexpr (SUB1) {   // drop raw row rr-5 (same constexpr slot I)
        float o0 = st.r1[I][0], o1 = st.r1[I][1], o2 = st.r1[I][2];
        float o3 = st.r1[I][3], o4 = st.r1[I][4], o5 = st.r1[I][5];
        st.V1[0] -= o0; st.V1[1] -= o1; st.V1[2] -= o2;
        st.V1[3] -= o3; st.V1[4] -= o4; st.V1[5] -= o5;
        st.V1[6]  -= o0 * o0; st.V1[7]  -= o0 * o1; st.V1[8]  -= o0 * o2;
        st.V1[9]  -= o1 * o1; st.V1[10] -= o1 * o2; st.V1[11] -= o2 * o2;
        st.V1[12] -= o0 * o3; st.V1[13] -= o0 * o4; st.V1[14] -= o0 * o5;
        st.V1[15] -= o1 * o3; st.V1[16] -= o1 * o4; st.V1[17] -= o1 * o5;
        st.V1[18] -= o2 * o3; st.V1[19] -= o2 * o4; st.V1[20] -= o2 * o5;
    }
    st.r1[I][0] = c0; st.r1[I][1] = c1; st.r1[I][2] = c2;
    st.r1[I][3] = c3; st.r1[I][4] = c4; st.r1[I][5] = c5;

    if constexpr (SOLVE) {
        // ---- stage 1 finalize: a-row at y = yb + rr - 6, a-col XA0+lane ----
        float S[21];
#pragma unroll
        for (int c = 0; c < 21; ++c) S[c] = hsum5(st.V1[c]);

        const float nrm = 0.04f;  // 1/25
        float mI0 = S[0] * nrm, mI1 = S[1] * nrm, mI2 = S[2] * nrm;
        float mP0 = S[3] * nrm, mP1 = S[4] * nrm, mP2 = S[5] * nrm;
        float v00 = S[6]  * nrm - mI0 * mI0 + GEPS;
        float v01 = S[7]  * nrm - mI0 * mI1;
        float v02 = S[8]  * nrm - mI0 * mI2;
        float v11 = S[9]  * nrm - mI1 * mI1 + GEPS;
        float v12 = S[10] * nrm - mI1 * mI2;
        float v22 = S[11] * nrm - mI2 * mI2 + GEPS;
        float c00 = S[12] * nrm - mI0 * mP0;
        float c01 = S[13] * nrm - mI0 * mP1;
        float c02 = S[14] * nrm - mI0 * mP2;
        float c10 = S[15] * nrm - mI1 * mP0;
        float c11 = S[16] * nrm - mI1 * mP1;
        float c12 = S[17] * nrm - mI1 * mP2;
        float c20 = S[18] * nrm - mI2 * mP0;
        float c21 = S[19] * nrm - mI2 * mP1;
        float c22 = S[20] * nrm - mI2 * mP2;
        // symmetric 3x3 inverse via adjugate (A PD: PSD + eps*I)
        float i00 = v11 * v22 - v12 * v12;
        float i01 = v02 * v12 - v01 * v22;
        float i02 = v01 * v12 - v02 * v11;
        float i11 = v00 * v22 - v02 * v02;
        float i12 = v01 * v02 - v00 * v12;
        float i22 = v00 * v11 - v01 * v01;
        float det = v00 * i00 + v01 * i01 + v02 * i02;
        float rd  = __builtin_amdgcn_rcpf(det);   // ~1e-7 rel err, fine vs 0.019 threshold
        float a00 = (i00 * c00 + i01 * c10 + i02 * c20) * rd;
        float a01 = (i00 * c01 + i01 * c11 + i02 * c21) * rd;
        float a02 = (i00 * c02 + i01 * c12 + i02 * c22) * rd;
        float a10 = (i01 * c00 + i11 * c10 + i12 * c20) * rd;
        float a11 = (i01 * c01 + i11 * c11 + i12 * c21) * rd;
        float a12 = (i01 * c02 + i11 * c12 + i12 * c22) * rd;
        float a20 = (i02 * c00 + i12 * c10 + i22 * c20) * rd;
        float a21 = (i02 * c01 + i12 * c11 + i22 * c21) * rd;
        float a22 = (i02 * c02 + i12 * c12 + i22 * c22) * rd;
        float b0 = mP0 - (a00 * mI0 + a10 * mI1 + a20 * mI2);
        float b1 = mP1 - (a01 * mI0 + a11 * mI1 + a21 * mI2);
        float b2 = mP2 - (a02 * mI0 + a12 * mI1 + a22 * mI2);

        // ---- stage 2: horizontal 5-tap of a,b now; vertical roll ----
        float hv[12];
        hv[0] = hsum5(a00); hv[1]  = hsum5(a01); hv[2]  = hsum5(a02);
        hv[3] = hsum5(a10); hv[4]  = hsum5(a11); hv[5]  = hsum5(a12);
        hv[6] = hsum5(a20); hv[7]  = hsum5(a21); hv[8]  = hsum5(a22);
        hv[9] = hsum5(b0);  hv[10] = hsum5(b1);  hv[11] = hsum5(b2);

#pragma unroll
        for (int c = 0; c < 12; ++c) {
            st.V2[c] += hv[c];
            if constexpr (V2SUB) st.V2[c] -= st.r2[I][c];  // read old before overwrite
            st.r2[I][c] = hv[c];
        }

        if constexpr (OUT) {
            // output row yo = yb + rr - 8, col xo; mean = V2 / 25
            float M[12];
#pragma unroll
            for (int c = 0; c < 12; ++c) M[c] = st.V2[c] * 0.04f;
            float o0 = go0 * M[0] + go1 * M[3] + go2 * M[6] + M[9];
            float o1 = go0 * M[1] + go1 * M[4] + go2 * M[7] + M[10];
            float o2 = go0 * M[2] + go1 * M[5] + go2 * M[8] + M[11];
            if (cx.wr) {
                cx.o0[oOff] = o0;
                cx.o1[oOff] = o1;
                cx.o2[oOff] = o2;
            }
        }
    }
}

__global__ __launch_bounds__(64, 2) void fused_kernel(
        const float* __restrict__ g, const float* __restrict__ p,
        float* __restrict__ out) {
    const int lane = threadIdx.x;       // 64 threads = 1 wave
    const int bb   = blockIdx.z;

    // a-col of lane u: XA0 + u, XA0 = bx*56 - 2
    // raw col:  XA0 + u - 2 (reflected); output col: XA0 + u + 2 = bx*56 + u
    const int XA0 = blockIdx.x * OUTW - 2;
    const int xrq = XA0 + lane - 2;
    const int xo  = XA0 + lane + 2;

    Ctx cx;
    cx.g0 = g + (size_t)bb * 3 * CSZ; cx.g1 = cx.g0 + CSZ; cx.g2 = cx.g0 + 2 * CSZ;
    cx.p0 = p + (size_t)bb * 3 * CSZ; cx.p1 = cx.p0 + CSZ; cx.p2 = cx.p0 + 2 * CSZ;
    cx.o0 = out + (size_t)bb * 3 * CSZ; cx.o1 = cx.o0 + CSZ; cx.o2 = cx.o0 + 2 * CSZ;
    cx.yb = blockIdx.y * SR;
    cx.xr = refl(xrq, WW);
    cx.xs = (xo < WW) ? xo : (WW - 1);
    cx.wr = (lane < OUTW) && (xo < WW);

    St st;
#pragma unroll
    for (int i = 0; i < 21; ++i) st.V1[i] = 0.f;
#pragma unroll
    for (int i = 0; i < 12; ++i) st.V2[i] = 0.f;

    // 24 raw rows total (rr = 0..23); outputs at rr = 8..23 -> rows yb..yb+15.
    // trip 0: rows 0..4 — accumulate; first solve at rr=4
    row<0, false, false, false, false>(st, cx, 0);
    row<1, false, false, false, false>(st, cx, 0);
    row<2, false, false, false, false>(st, cx, 0);
    row<3, false, false, false, false>(st, cx, 0);
    row<4, false, true,  false, false>(st, cx, 0);
    // trip 1: rows 5..9 — first outputs at rr=8,9; first V2-sub at rr=9
    row<0, true, true, false, false>(st, cx, 1);
    row<1, true, true, false, false>(st, cx, 1);
    row<2, true, true, false, false>(st, cx, 1);
    row<3, true, true, false, true >(st, cx, 1);
    row<4, true, true, true,  true >(st, cx, 1);
    // steady trips: rows 10..19
#pragma unroll 1
    for (int t = 2; t <= 3; ++t) {
        row<0, true, true, true, true>(st, cx, t);
        row<1, true, true, true, true>(st, cx, t);
        row<2, true, true, true, true>(st, cx, t);
        row<3, true, true, true, true>(st, cx, t);
        row<4, true, true, true, true>(st, cx, t);
    }
    // tail trip: rows 20..23 (last output rr=23 -> yo=yb+15)
    row<0, true, true, true, true>(st, cx, 4);
    row<1, true, true, true, true>(st, cx, 4);
    row<2, true, true, true, true>(st, cx, 4);
    row<3, true, true, true, true>(st, cx, 4);
}

}  // namespace

extern "C" void kernel_launch(void* const* d_in, const int* in_sizes, int n_in,
                              void* d_out, int out_size, void* d_ws, size_t ws_size,
                              hipStream_t stream) {
    const float* g  = (const float*)d_in[0];   // guidance [8,3,512,512]
    const float* p  = (const float*)d_in[1];   // input    [8,3,512,512]
    float* out = (float*)d_out;                // [8,3,512,512]

    // 10 col-strips of 56 (last covers cols 504..511), 32 row-strips of 16, 8 batches
    dim3 grid((WW + OUTW - 1) / OUTW, HH / SR, BN);   // (10, 32, 8) = 2560 blocks
    dim3 block(64);

    hipLaunchKernelGGL(fused_kernel, grid, block, 0, stream, g, p, out);
}

// Round 11
// 134.535 us; speedup vs baseline: 1.0576x; 1.0576x over previous
//
#include <hip/hip_runtime.h>

// Guided blur (multichannel guided filter), B=8, C=Cp=3, H=W=512, k=5, eps=1e-4.
// SINGLE fused kernel, LDS-free, barrier-free, 16-lane-row DPP horizontal taps,
// 1-row software prefetch:
//   - wave = 4 x 16-lane segments; each segment: 16 raw cols, 12 valid a-cols, 8 output cols
//   - horizontal 5-taps via v_add + DPP row_shl:{1,2,4} (VALU pipe; proven fast r4-r9.
//     r10 lesson: wave_shl1 (ctrl 0x130) runs at a fraction of VALU rate on gfx950 -> 2.2x
//     regression. Stay within 16-lane rows.)
//   - stage 1: vertical 5-row roll of 21 stat channels -> hsum5 -> symmetric 3x3 solve -> a,b
//   - stage 2: hsum5 of a,b; vertical 5-row roll of those 12 -> combine with guidance -> out
//   - NEW (this round): raw-row loads are software-pipelined 1 row ahead (P[6] in St):
//     iteration consumes registers, issues next row's 6 loads immediately -> a full
//     iteration (~900 issue-cycles at 2 waves/SIMD) between load and first use, hiding
//     L2/HBM latency that r6 exposed at every row (r6 VALUBusy 56%).
//   - trips of 5 rows, template<int I>: all ring indices compile-time => SROA keeps rings
//     in VGPRs.
//   Compile-shape lessons (this session):
//     r5: runtime ring idx -> PromoteAlloca-to-LDS -> 40us LDS-pipe serialization
//     r7: f2 ext-vector arrays in state struct -> failed SROA -> scratch spill (159us)
//     r8: __launch_bounds__(128,4) -> forced 64-VGPR cap -> 440MB spill traffic (213us)
//     r10: wave_shl1 DPP -> VALUBusy 21%, 160us
//   Proven safe form: scalar floats, constexpr indices, block=64, __launch_bounds__(64,2),
//   SR=32 geometry (r6: 69.5us best).
// No d_ws usage.

namespace {

constexpr int BN = 8;
constexpr int HH = 512;
constexpr int WW = 512;
constexpr int CSZ = HH * WW;
constexpr float GEPS = 1e-4f;
constexpr int SEGW = 8;             // output cols per 16-lane segment
constexpr int OUTW = 4 * SEGW;      // 32 output cols per wave
constexpr int SR   = 32;            // output rows per wave strip (reads SR+8 raw rows)
constexpr int NTRIP = (SR + 8) / 5; // 8 trips x 5 raw rows = 40 rows

__device__ __forceinline__ int refl(int i, int n) {
    // jnp.pad reflect: -1 -> 1, -2 -> 2, n -> n-2, n+1 -> n-3
    if (i < 0) i = -i;
    if (i >= n) i = 2 * n - 2 - i;
    return i;
}

// DPP row_shl:N within each 16-lane row: lane u receives lane u+N (0 past row end).
template <int N>
__device__ __forceinline__ float shlN(float v) {
    return __builtin_bit_cast(float,
        __builtin_amdgcn_update_dpp(0, __builtin_bit_cast(int, v),
                                    0x100 + N, 0xF, 0xF, true));
}
// row-local lane u gets v[u]+v[u+1]+v[u+2]+v[u+3]+v[u+4]; valid for u <= 11.
__device__ __forceinline__ float hsum5(float v) {
    float t = v + shlN<1>(v);
    float q = t + shlN<2>(t);
    return q + shlN<4>(v);
}

struct St {
    float P[6];        // prefetched next raw row (6 channels)
    float V1[21];      // stage-1 vertical window sums (21 stat channels)
    float r1[5][6];    // last 5 raw rows (6 channels)
    float V2[12];      // stage-2 vertical sums of hsum'd a,b
    float r2[5][12];   // last 5 hsum'd a,b rows
};

struct Ctx {
    const float *g0, *g1, *g2, *p0, *p1, *p2;  // channel base pointers
    float *o0, *o1, *o2;
    int yb, xr, xs;
    bool wr;
};

// One raw row. rr = 5*t + I. Ring slots use constexpr I ((5t+I)%5 == I).
// Consumes St::P (prefetched); if PF, issues loads for row rr+1 into St::P.
template <int I, bool SUB1, bool SOLVE, bool V2SUB, bool OUT, bool PF>
__device__ __forceinline__ void row(St& st, const Ctx& cx, int t) {
    const int rr = 5 * t + I;

    // capture current row from the prefetch buffer BEFORE overwriting it
    float c0 = st.P[0], c1 = st.P[1], c2 = st.P[2];
    float c3 = st.P[3], c4 = st.P[4], c5 = st.P[5];

    if constexpr (PF) {   // issue next row's loads now; first use is next iteration
        const int yn = refl(cx.yb - 4 + rr + 1, HH);
        const int offn = yn * WW + cx.xr;
        st.P[0] = cx.g0[offn]; st.P[1] = cx.g1[offn]; st.P[2] = cx.g2[offn];
        st.P[3] = cx.p0[offn]; st.P[4] = cx.p1[offn]; st.P[5] = cx.p2[offn];
    }

    // guidance for this iter's output row — issued early to cover latency
    float go0 = 0.f, go1 = 0.f, go2 = 0.f;
    int oOff = 0;
    if constexpr (OUT) {
        oOff = (cx.yb + rr - 8) * WW + cx.xs;
        go0 = cx.g0[oOff]; go1 = cx.g1[oOff]; go2 = cx.g2[oOff];
    }

    // add current raw row
    st.V1[0] += c0; st.V1[1] += c1; st.V1[2] += c2;
    st.V1[3] += c3; st.V1[4] += c4; st.V1[5] += c5;
    st.V1[6]  += c0 * c0; st.V1[7]  += c0 * c1; st.V1[8]  += c0 * c2;
    st.V1[9]  += c1 * c1; st.V1[10] += c1 * c2; st.V1[11] += c2 * c2;
    st.V1[12] += c0 * c3; st.V1[13] += c0 * c4; st.V1[14] += c0 * c5;
    st.V1[15] += c1 * c3; st.V1[16] += c1 * c4; st.V1[17] += c1 * c5;
    st.V1[18] += c2 * c3; st.V1[19] += c2 * c4; st.V1[20] += c2 * c5;

    if constexpr (SUB1) {   // drop raw row rr-5 (same constexpr slot I)
        float o0 = st.r1[I][0], o1 = st.r1[I][1], o2 = st.r1[I][2];
        float o3 = st.r1[I][3], o4 = st.r1[I][4], o5 = st.r1[I][5];
        st.V1[0] -= o0; st.V1[1] -= o1; st.V1[2] -= o2;
        st.V1[3] -= o3; st.V1[4] -= o4; st.V1[5] -= o5;
        st.V1[6]  -= o0 * o0; st.V1[7]  -= o0 * o1; st.V1[8]  -= o0 * o2;
        st.V1[9]  -= o1 * o1; st.V1[10] -= o1 * o2; st.V1[11] -= o2 * o2;
        st.V1[12] -= o0 * o3; st.V1[13] -= o0 * o4; st.V1[14] -= o0 * o5;
        st.V1[15] -= o1 * o3; st.V1[16] -= o1 * o4; st.V1[17] -= o1 * o5;
        st.V1[18] -= o2 * o3; st.V1[19] -= o2 * o4; st.V1[20] -= o2 * o5;
    }
    st.r1[I][0] = c0; st.r1[I][1] = c1; st.r1[I][2] = c2;
    st.r1[I][3] = c3; st.r1[I][4] = c4; st.r1[I][5] = c5;

    if constexpr (SOLVE) {
        // ---- stage 1 finalize: a-row at y = yb + rr - 6, a-col xbase+l ----
        float S[21];
#pragma unroll
        for (int c = 0; c < 21; ++c) S[c] = hsum5(st.V1[c]);

        const float nrm = 0.04f;  // 1/25
        float mI0 = S[0] * nrm, mI1 = S[1] * nrm, mI2 = S[2] * nrm;
        float mP0 = S[3] * nrm, mP1 = S[4] * nrm, mP2 = S[5] * nrm;
        float v00 = S[6]  * nrm - mI0 * mI0 + GEPS;
        float v01 = S[7]  * nrm - mI0 * mI1;
        float v02 = S[8]  * nrm - mI0 * mI2;
        float v11 = S[9]  * nrm - mI1 * mI1 + GEPS;
        float v12 = S[10] * nrm - mI1 * mI2;
        float v22 = S[11] * nrm - mI2 * mI2 + GEPS;
        float c00 = S[12] * nrm - mI0 * mP0;
        float c01 = S[13] * nrm - mI0 * mP1;
        float c02 = S[14] * nrm - mI0 * mP2;
        float c10 = S[15] * nrm - mI1 * mP0;
        float c11 = S[16] * nrm - mI1 * mP1;
        float c12 = S[17] * nrm - mI1 * mP2;
        float c20 = S[18] * nrm - mI2 * mP0;
        float c21 = S[19] * nrm - mI2 * mP1;
        float c22 = S[20] * nrm - mI2 * mP2;
        // symmetric 3x3 inverse via adjugate (A PD: PSD + eps*I)
        float i00 = v11 * v22 - v12 * v12;
        float i01 = v02 * v12 - v01 * v22;
        float i02 = v01 * v12 - v02 * v11;
        float i11 = v00 * v22 - v02 * v02;
        float i12 = v01 * v02 - v00 * v12;
        float i22 = v00 * v11 - v01 * v01;
        float det = v00 * i00 + v01 * i01 + v02 * i02;
        float rd  = __builtin_amdgcn_rcpf(det);   // ~1e-7 rel err, fine vs 0.019 threshold
        float a00 = (i00 * c00 + i01 * c10 + i02 * c20) * rd;
        float a01 = (i00 * c01 + i01 * c11 + i02 * c21) * rd;
        float a02 = (i00 * c02 + i01 * c12 + i02 * c22) * rd;
        float a10 = (i01 * c00 + i11 * c10 + i12 * c20) * rd;
        float a11 = (i01 * c01 + i11 * c11 + i12 * c21) * rd;
        float a12 = (i01 * c02 + i11 * c12 + i12 * c22) * rd;
        float a20 = (i02 * c00 + i12 * c10 + i22 * c20) * rd;
        float a21 = (i02 * c01 + i12 * c11 + i22 * c21) * rd;
        float a22 = (i02 * c02 + i12 * c12 + i22 * c22) * rd;
        float b0 = mP0 - (a00 * mI0 + a10 * mI1 + a20 * mI2);
        float b1 = mP1 - (a01 * mI0 + a11 * mI1 + a21 * mI2);
        float b2 = mP2 - (a02 * mI0 + a12 * mI1 + a22 * mI2);

        // ---- stage 2: horizontal 5-tap of a,b now; vertical roll ----
        float hv[12];
        hv[0] = hsum5(a00); hv[1]  = hsum5(a01); hv[2]  = hsum5(a02);
        hv[3] = hsum5(a10); hv[4]  = hsum5(a11); hv[5]  = hsum5(a12);
        hv[6] = hsum5(a20); hv[7]  = hsum5(a21); hv[8]  = hsum5(a22);
        hv[9] = hsum5(b0);  hv[10] = hsum5(b1);  hv[11] = hsum5(b2);

#pragma unroll
        for (int c = 0; c < 12; ++c) {
            st.V2[c] += hv[c];
            if constexpr (V2SUB) st.V2[c] -= st.r2[I][c];  // read old before overwrite
            st.r2[I][c] = hv[c];
        }

        if constexpr (OUT) {
            // output row yo = yb + rr - 8, col xo; mean = V2 / 25
            float M[12];
#pragma unroll
            for (int c = 0; c < 12; ++c) M[c] = st.V2[c] * 0.04f;
            float o0 = go0 * M[0] + go1 * M[3] + go2 * M[6] + M[9];
            float o1 = go0 * M[1] + go1 * M[4] + go2 * M[7] + M[10];
            float o2 = go0 * M[2] + go1 * M[5] + go2 * M[8] + M[11];
            if (cx.wr) {
                cx.o0[oOff] = o0;
                cx.o1[oOff] = o1;
                cx.o2[oOff] = o2;
            }
        }
    }
}

__global__ __launch_bounds__(64, 2) void fused_kernel(
        const float* __restrict__ g, const float* __restrict__ p,
        float* __restrict__ out) {
    const int lane = threadIdx.x;       // 64 threads = 1 wave
    const int l    = lane & 15;
    const int seg  = lane >> 4;
    const int XO   = blockIdx.x * OUTW;
    const int bb   = blockIdx.z;

    const int xbase = XO + seg * SEGW - 2;          // a-col of row-local lane 0
    const int xrq   = xbase + l - 2;                // raw read col (pre-reflect)
    const int xo    = xbase + l + 2;                // output col (valid l < SEGW)

    Ctx cx;
    cx.g0 = g + (size_t)bb * 3 * CSZ; cx.g1 = cx.g0 + CSZ; cx.g2 = cx.g0 + 2 * CSZ;
    cx.p0 = p + (size_t)bb * 3 * CSZ; cx.p1 = cx.p0 + CSZ; cx.p2 = cx.p0 + 2 * CSZ;
    cx.o0 = out + (size_t)bb * 3 * CSZ; cx.o1 = cx.o0 + CSZ; cx.o2 = cx.o0 + 2 * CSZ;
    cx.yb = blockIdx.y * SR;
    cx.xr = refl(xrq, WW);
    cx.xs = (xo < WW) ? xo : (WW - 1);
    cx.wr = (l < SEGW);                             // xo < 512 guaranteed for l < SEGW

    St st;
#pragma unroll
    for (int i = 0; i < 21; ++i) st.V1[i] = 0.f;
#pragma unroll
    for (int i = 0; i < 12; ++i) st.V2[i] = 0.f;

    // prime the prefetch buffer with raw row 0
    {
        const int y0 = refl(cx.yb - 4, HH);
        const int off0 = y0 * WW + cx.xr;
        st.P[0] = cx.g0[off0]; st.P[1] = cx.g1[off0]; st.P[2] = cx.g2[off0];
        st.P[3] = cx.p0[off0]; st.P[4] = cx.p1[off0]; st.P[5] = cx.p2[off0];
    }

    // 40 raw rows total (rr = 0..39); outputs at rr = 8..39 -> rows yb..yb+31.
    // trip 0: rows 0..4 — accumulate; first solve at rr=4
    row<0, false, false, false, false, true>(st, cx, 0);
    row<1, false, false, false, false, true>(st, cx, 0);
    row<2, false, false, false, false, true>(st, cx, 0);
    row<3, false, false, false, false, true>(st, cx, 0);
    row<4, false, true,  false, false, true>(st, cx, 0);
    // trip 1: rows 5..9 — first outputs at rr=8,9; first V2-sub at rr=9
    row<0, true, true, false, false, true>(st, cx, 1);
    row<1, true, true, false, false, true>(st, cx, 1);
    row<2, true, true, false, false, true>(st, cx, 1);
    row<3, true, true, false, true,  true>(st, cx, 1);
    row<4, true, true, true,  true,  true>(st, cx, 1);
    // steady trips: rows 10..34
#pragma unroll 1
    for (int t = 2; t <= 6; ++t) {
        row<0, true, true, true, true, true>(st, cx, t);
        row<1, true, true, true, true, true>(st, cx, t);
        row<2, true, true, true, true, true>(st, cx, t);
        row<3, true, true, true, true, true>(st, cx, t);
        row<4, true, true, true, true, true>(st, cx, t);
    }
    // tail trip 7: rows 35..39 (last row: no prefetch)
    row<0, true, true, true, true, true >(st, cx, 7);
    row<1, true, true, true, true, true >(st, cx, 7);
    row<2, true, true, true, true, true >(st, cx, 7);
    row<3, true, true, true, true, true >(st, cx, 7);
    row<4, true, true, true, true, false>(st, cx, 7);
}

}  // namespace

extern "C" void kernel_launch(void* const* d_in, const int* in_sizes, int n_in,
                              void* d_out, int out_size, void* d_ws, size_t ws_size,
                              hipStream_t stream) {
    const float* g  = (const float*)d_in[0];   // guidance [8,3,512,512]
    const float* p  = (const float*)d_in[1];   // input    [8,3,512,512]
    float* out = (float*)d_out;                // [8,3,512,512]

    dim3 grid(WW / OUTW, HH / SR, BN);         // (16, 16, 8) = 2048 single-wave blocks
    dim3 block(64);

    hipLaunchKernelGGL(fused_kernel, grid, block, 0, stream, g, p, out);
}

// Round 12
// 129.575 us; speedup vs baseline: 1.0981x; 1.0383x over previous
//
#include <hip/hip_runtime.h>

// Guided blur (multichannel guided filter), B=8, C=Cp=3, H=W=512, k=5, eps=1e-4.
// SINGLE fused kernel, LDS-free, barrier-free, 16-lane-row DPP horizontal taps,
// FULL 9-load software pipeline (raw rows + output-row guidance both prefetched):
//   - wave = 4 x 16-lane segments; each segment: 16 raw cols, 12 valid a-cols, 8 output cols
//   - horizontal 5-taps via v_add + DPP row_shl:{1,2,4} (VALU pipe; proven fast r4-r11.
//     r10 lesson: wave_shl1 (ctrl 0x130) runs far below VALU rate on gfx950 -> 2.2x regress)
//   - stage 1: vertical 5-row roll of 21 stat channels -> hsum5 -> symmetric 3x3 solve -> a,b
//   - stage 2: hsum5 of a,b; vertical 5-row roll of those 12 -> combine with guidance -> out
//   - r12 change (vmcnt pipeline fix): r11 issued the 6 raw prefetch loads BEFORE this
//     iter's 3 guidance loads; waiting on the (newest) guidance loads at the output combine
//     forces vmcnt(0), draining the just-issued prefetch -> ~L2 latency stall EVERY iter.
//     Now guidance for iter rr+1's output row is prefetched into Pg[3] alongside the raw
//     prefetch: all 9 loads issued contiguously, consumed next iteration, one maximally
//     distant waitcnt per iter.
//   - trips of 5 rows, template<int I>: all ring indices compile-time => SROA keeps rings
//     in VGPRs.
//   Compile-shape lessons (this session):
//     r5: runtime ring idx -> PromoteAlloca-to-LDS -> 40us LDS-pipe serialization
//     r7: f2 ext-vector arrays in state struct -> failed SROA -> scratch spill (159us)
//     r8: __launch_bounds__(128,4) -> forced 64-VGPR cap -> 440MB spill traffic (213us)
//     r10: wave_shl1 DPP -> VALUBusy 21%, 160us
//     r9/r11: VALUBusy pinned ~57% at 2 AND 4 waves/SIMD -> per-wave stall, not occupancy
//   Proven safe form: scalar floats, constexpr indices, block=64, __launch_bounds__(64,2),
//   SR=32 geometry.
// No d_ws usage.

namespace {

constexpr int BN = 8;
constexpr int HH = 512;
constexpr int WW = 512;
constexpr int CSZ = HH * WW;
constexpr float GEPS = 1e-4f;
constexpr int SEGW = 8;             // output cols per 16-lane segment
constexpr int OUTW = 4 * SEGW;      // 32 output cols per wave
constexpr int SR   = 32;            // output rows per wave strip (reads SR+8 raw rows)

__device__ __forceinline__ int refl(int i, int n) {
    // jnp.pad reflect: -1 -> 1, -2 -> 2, n -> n-2, n+1 -> n-3
    if (i < 0) i = -i;
    if (i >= n) i = 2 * n - 2 - i;
    return i;
}

// DPP row_shl:N within each 16-lane row: lane u receives lane u+N (0 past row end).
template <int N>
__device__ __forceinline__ float shlN(float v) {
    return __builtin_bit_cast(float,
        __builtin_amdgcn_update_dpp(0, __builtin_bit_cast(int, v),
                                    0x100 + N, 0xF, 0xF, true));
}
// row-local lane u gets v[u]+v[u+1]+v[u+2]+v[u+3]+v[u+4]; valid for u <= 11.
__device__ __forceinline__ float hsum5(float v) {
    float t = v + shlN<1>(v);
    float q = t + shlN<2>(t);
    return q + shlN<4>(v);
}

struct St {
    float P[6];        // prefetched next raw row (6 channels)
    float Pg[3];       // prefetched guidance for NEXT iter's output row
    float V1[21];      // stage-1 vertical window sums (21 stat channels)
    float r1[5][6];    // last 5 raw rows (6 channels)
    float V2[12];      // stage-2 vertical sums of hsum'd a,b
    float r2[5][12];   // last 5 hsum'd a,b rows
};

struct Ctx {
    const float *g0, *g1, *g2, *p0, *p1, *p2;  // channel base pointers
    float *o0, *o1, *o2;
    int yb, xr, xs;
    bool wr;
};

// One raw row. rr = 5*t + I. Ring slots use constexpr I ((5t+I)%5 == I).
// Consumes St::P / St::Pg (prefetched last iter); if PF/PG, issues next iter's loads.
template <int I, bool SUB1, bool SOLVE, bool V2SUB, bool OUT, bool PF, bool PG>
__device__ __forceinline__ void row(St& st, const Ctx& cx, int t) {
    const int rr = 5 * t + I;

    // capture current values from prefetch buffers BEFORE overwriting them
    float c0 = st.P[0], c1 = st.P[1], c2 = st.P[2];
    float c3 = st.P[3], c4 = st.P[4], c5 = st.P[5];
    float gg0 = 0.f, gg1 = 0.f, gg2 = 0.f;
    int oOff = 0;
    if constexpr (OUT) {
        oOff = (cx.yb + rr - 8) * WW + cx.xs;
        gg0 = st.Pg[0]; gg1 = st.Pg[1]; gg2 = st.Pg[2];
    }

    if constexpr (PF) {   // next raw row; first use is next iteration
        const int yn = refl(cx.yb - 4 + rr + 1, HH);
        const int offn = yn * WW + cx.xr;
        st.P[0] = cx.g0[offn]; st.P[1] = cx.g1[offn]; st.P[2] = cx.g2[offn];
        st.P[3] = cx.p0[offn]; st.P[4] = cx.p1[offn]; st.P[5] = cx.p2[offn];
    }
    if constexpr (PG) {   // guidance for next iter's output row yb + (rr+1) - 8
        const int offg = (cx.yb + rr - 7) * WW + cx.xs;
        st.Pg[0] = cx.g0[offg]; st.Pg[1] = cx.g1[offg]; st.Pg[2] = cx.g2[offg];
    }

    // add current raw row
    st.V1[0] += c0; st.V1[1] += c1; st.V1[2] += c2;
    st.V1[3] += c3; st.V1[4] += c4; st.V1[5] += c5;
    st.V1[6]  += c0 * c0; st.V1[7]  += c0 * c1; st.V1[8]  += c0 * c2;
    st.V1[9]  += c1 * c1; st.V1[10] += c1 * c2; st.V1[11] += c2 * c2;
    st.V1[12] += c0 * c3; st.V1[13] += c0 * c4; st.V1[14] += c0 * c5;
    st.V1[15] += c1 * c3; st.V1[16] += c1 * c4; st.V1[17] += c1 * c5;
    st.V1[18] += c2 * c3; st.V1[19] += c2 * c4; st.V1[20] += c2 * c5;

    if constexpr (SUB1) {   // drop raw row rr-5 (same constexpr slot I)
        float o0 = st.r1[I][0], o1 = st.r1[I][1], o2 = st.r1[I][2];
        float o3 = st.r1[I][3], o4 = st.r1[I][4], o5 = st.r1[I][5];
        st.V1[0] -= o0; st.V1[1] -= o1; st.V1[2] -= o2;
        st.V1[3] -= o3; st.V1[4] -= o4; st.V1[5] -= o5;
        st.V1[6]  -= o0 * o0; st.V1[7]  -= o0 * o1; st.V1[8]  -= o0 * o2;
        st.V1[9]  -= o1 * o1; st.V1[10] -= o1 * o2; st.V1[11] -= o2 * o2;
        st.V1[12] -= o0 * o3; st.V1[13] -= o0 * o4; st.V1[14] -= o0 * o5;
        st.V1[15] -= o1 * o3; st.V1[16] -= o1 * o4; st.V1[17] -= o1 * o5;
        st.V1[18] -= o2 * o3; st.V1[19] -= o2 * o4; st.V1[20] -= o2 * o5;
    }
    st.r1[I][0] = c0; st.r1[I][1] = c1; st.r1[I][2] = c2;
    st.r1[I][3] = c3; st.r1[I][4] = c4; st.r1[I][5] = c5;

    if constexpr (SOLVE) {
        // ---- stage 1 finalize: a-row at y = yb + rr - 6, a-col xbase+l ----
        float S[21];
#pragma unroll
        for (int c = 0; c < 21; ++c) S[c] = hsum5(st.V1[c]);

        const float nrm = 0.04f;  // 1/25
        float mI0 = S[0] * nrm, mI1 = S[1] * nrm, mI2 = S[2] * nrm;
        float mP0 = S[3] * nrm, mP1 = S[4] * nrm, mP2 = S[5] * nrm;
        float v00 = S[6]  * nrm - mI0 * mI0 + GEPS;
        float v01 = S[7]  * nrm - mI0 * mI1;
        float v02 = S[8]  * nrm - mI0 * mI2;
        float v11 = S[9]  * nrm - mI1 * mI1 + GEPS;
        float v12 = S[10] * nrm - mI1 * mI2;
        float v22 = S[11] * nrm - mI2 * mI2 + GEPS;
        float c00 = S[12] * nrm - mI0 * mP0;
        float c01 = S[13] * nrm - mI0 * mP1;
        float c02 = S[14] * nrm - mI0 * mP2;
        float c10 = S[15] * nrm - mI1 * mP0;
        float c11 = S[16] * nrm - mI1 * mP1;
        float c12 = S[17] * nrm - mI1 * mP2;
        float c20 = S[18] * nrm - mI2 * mP0;
        float c21 = S[19] * nrm - mI2 * mP1;
        float c22 = S[20] * nrm - mI2 * mP2;
        // symmetric 3x3 inverse via adjugate (A PD: PSD + eps*I)
        float i00 = v11 * v22 - v12 * v12;
        float i01 = v02 * v12 - v01 * v22;
        float i02 = v01 * v12 - v02 * v11;
        float i11 = v00 * v22 - v02 * v02;
        float i12 = v01 * v02 - v00 * v12;
        float i22 = v00 * v11 - v01 * v01;
        float det = v00 * i00 + v01 * i01 + v02 * i02;
        float rd  = __builtin_amdgcn_rcpf(det);   // ~1e-7 rel err, fine vs 0.019 threshold
        float a00 = (i00 * c00 + i01 * c10 + i02 * c20) * rd;
        float a01 = (i00 * c01 + i01 * c11 + i02 * c21) * rd;
        float a02 = (i00 * c02 + i01 * c12 + i02 * c22) * rd;
        float a10 = (i01 * c00 + i11 * c10 + i12 * c20) * rd;
        float a11 = (i01 * c01 + i11 * c11 + i12 * c21) * rd;
        float a12 = (i01 * c02 + i11 * c12 + i12 * c22) * rd;
        float a20 = (i02 * c00 + i12 * c10 + i22 * c20) * rd;
        float a21 = (i02 * c01 + i12 * c11 + i22 * c21) * rd;
        float a22 = (i02 * c02 + i12 * c12 + i22 * c22) * rd;
        float b0 = mP0 - (a00 * mI0 + a10 * mI1 + a20 * mI2);
        float b1 = mP1 - (a01 * mI0 + a11 * mI1 + a21 * mI2);
        float b2 = mP2 - (a02 * mI0 + a12 * mI1 + a22 * mI2);

        // ---- stage 2: horizontal 5-tap of a,b now; vertical roll ----
        float hv[12];
        hv[0] = hsum5(a00); hv[1]  = hsum5(a01); hv[2]  = hsum5(a02);
        hv[3] = hsum5(a10); hv[4]  = hsum5(a11); hv[5]  = hsum5(a12);
        hv[6] = hsum5(a20); hv[7]  = hsum5(a21); hv[8]  = hsum5(a22);
        hv[9] = hsum5(b0);  hv[10] = hsum5(b1);  hv[11] = hsum5(b2);

#pragma unroll
        for (int c = 0; c < 12; ++c) {
            st.V2[c] += hv[c];
            if constexpr (V2SUB) st.V2[c] -= st.r2[I][c];  // read old before overwrite
            st.r2[I][c] = hv[c];
        }

        if constexpr (OUT) {
            // output row yo = yb + rr - 8, col xo; mean = V2 / 25
            float M[12];
#pragma unroll
            for (int c = 0; c < 12; ++c) M[c] = st.V2[c] * 0.04f;
            float o0 = gg0 * M[0] + gg1 * M[3] + gg2 * M[6] + M[9];
            float o1 = gg0 * M[1] + gg1 * M[4] + gg2 * M[7] + M[10];
            float o2 = gg0 * M[2] + gg1 * M[5] + gg2 * M[8] + M[11];
            if (cx.wr) {
                cx.o0[oOff] = o0;
                cx.o1[oOff] = o1;
                cx.o2[oOff] = o2;
            }
        }
    }
}

__global__ __launch_bounds__(64, 2) void fused_kernel(
        const float* __restrict__ g, const float* __restrict__ p,
        float* __restrict__ out) {
    const int lane = threadIdx.x;       // 64 threads = 1 wave
    const int l    = lane & 15;
    const int seg  = lane >> 4;
    const int XO   = blockIdx.x * OUTW;
    const int bb   = blockIdx.z;

    const int xbase = XO + seg * SEGW - 2;          // a-col of row-local lane 0
    const int xrq   = xbase + l - 2;                // raw read col (pre-reflect)
    const int xo    = xbase + l + 2;                // output col (valid l < SEGW)

    Ctx cx;
    cx.g0 = g + (size_t)bb * 3 * CSZ; cx.g1 = cx.g0 + CSZ; cx.g2 = cx.g0 + 2 * CSZ;
    cx.p0 = p + (size_t)bb * 3 * CSZ; cx.p1 = cx.p0 + CSZ; cx.p2 = cx.p0 + 2 * CSZ;
    cx.o0 = out + (size_t)bb * 3 * CSZ; cx.o1 = cx.o0 + CSZ; cx.o2 = cx.o0 + 2 * CSZ;
    cx.yb = blockIdx.y * SR;
    cx.xr = refl(xrq, WW);
    cx.xs = (xo < WW) ? xo : (WW - 1);
    cx.wr = (l < SEGW);                             // xo < 512 guaranteed for l < SEGW

    St st;
#pragma unroll
    for (int i = 0; i < 21; ++i) st.V1[i] = 0.f;
#pragma unroll
    for (int i = 0; i < 12; ++i) st.V2[i] = 0.f;

    // prime the prefetch buffer with raw row 0
    {
        const int y0 = refl(cx.yb - 4, HH);
        const int off0 = y0 * WW + cx.xr;
        st.P[0] = cx.g0[off0]; st.P[1] = cx.g1[off0]; st.P[2] = cx.g2[off0];
        st.P[3] = cx.p0[off0]; st.P[4] = cx.p1[off0]; st.P[5] = cx.p2[off0];
    }

    // 40 raw rows total (rr = 0..39); outputs at rr = 8..39 -> rows yb..yb+31.
    // PG (guidance prefetch for rr+1's output) active for rr in [7, 38].
    // trip 0: rows 0..4 — accumulate; first solve at rr=4
    row<0, false, false, false, false, true, false>(st, cx, 0);
    row<1, false, false, false, false, true, false>(st, cx, 0);
    row<2, false, false, false, false, true, false>(st, cx, 0);
    row<3, false, false, false, false, true, false>(st, cx, 0);
    row<4, false, true,  false, false, true, false>(st, cx, 0);
    // trip 1: rows 5..9 — first outputs at rr=8,9 (PG starts at rr=7); first V2-sub at rr=9
    row<0, true, true, false, false, true, false>(st, cx, 1);
    row<1, true, true, false, false, true, false>(st, cx, 1);
    row<2, true, true, false, false, true, true >(st, cx, 1);
    row<3, true, true, false, true,  true, true >(st, cx, 1);
    row<4, true, true, true,  true,  true, true >(st, cx, 1);
    // steady trips: rows 10..34
#pragma unroll 1
    for (int t = 2; t <= 6; ++t) {
        row<0, true, true, true, true, true, true>(st, cx, t);
        row<1, true, true, true, true, true, true>(st, cx, t);
        row<2, true, true, true, true, true, true>(st, cx, t);
        row<3, true, true, true, true, true, true>(st, cx, t);
        row<4, true, true, true, true, true, true>(st, cx, t);
    }
    // tail trip 7: rows 35..39 (last row: no prefetches)
    row<0, true, true, true, true, true,  true >(st, cx, 7);
    row<1, true, true, true, true, true,  true >(st, cx, 7);
    row<2, true, true, true, true, true,  true >(st, cx, 7);
    row<3, true, true, true, true, true,  true >(st, cx, 7);
    row<4, true, true, true, true, false, false>(st, cx, 7);
}

}  // namespace

extern "C" void kernel_launch(void* const* d_in, const int* in_sizes, int n_in,
                              void* d_out, int out_size, void* d_ws, size_t ws_size,
                              hipStream_t stream) {
    const float* g  = (const float*)d_in[0];   // guidance [8,3,512,512]
    const float* p  = (const float*)d_in[1];   // input    [8,3,512,512]
    float* out = (float*)d_out;                // [8,3,512,512]

    dim3 grid(WW / OUTW, HH / SR, BN);         // (16, 16, 8) = 2048 single-wave blocks
    dim3 block(64);

    hipLaunchKernelGGL(fused_kernel, grid, block, 0, stream, g, p, out);
}